// Round 13
// baseline (101.588 us; speedup 1.0000x reference)
//
#include <hip/hip_runtime.h>
#include <hip/hip_bf16.h>
#include <cstddef>
#include <cstdint>

#define L_SEQ 2048
#define DM    1024
#define NREC  8

typedef __attribute__((ext_vector_type(8))) short short8;
typedef __attribute__((ext_vector_type(4))) float f32x4;
typedef __attribute__((ext_vector_type(2))) unsigned int u32x2;

// native conversion: compiler fuses adjacent casts into v_cvt_pk_bf16_f32 (RNE)
__device__ inline unsigned short f2bf(float f) {
    __hip_bfloat16 h = __float2bfloat16(f);
    return __builtin_bit_cast(unsigned short, h);
}
__device__ inline void gload_lds16(const void* g, void* l) {
    __builtin_amdgcn_global_load_lds(
        (const __attribute__((address_space(1))) void*)g,
        (__attribute__((address_space(3))) void*)l, 16, 0, 0);
}
__device__ inline short8 pack8(f32x4 x, f32x4 y) {
    short8 c;
    c[0] = (short)f2bf(x[0]); c[1] = (short)f2bf(x[1]);
    c[2] = (short)f2bf(x[2]); c[3] = (short)f2bf(x[3]);
    c[4] = (short)f2bf(y[0]); c[5] = (short)f2bf(y[1]);
    c[6] = (short)f2bf(y[2]); c[7] = (short)f2bf(y[3]);
    return c;
}

// ======== fused-cvt 256x128 GEMM: klin[b][h][l] = W[h][:].u[b][l][:] + bias
// r12's proven-stable fused structure, tile 256x256 -> 256x128 under the SAME
// allocator constraint __launch_bounds__(512,2) (VGPR cap 256 — r10's collapse
// was the (512,4)=128-cap, not the geometry). acc 64 + staged 24 + temps ~100
// VGPR -> 4 waves/SIMD; LDS 48 KB -> 2 blocks/CU; grid 512 = 2 blocks/CU so
// co-resident blocks hide each other's per-tile barrier + load chain.
// 8 waves as 4M x 2N (wave tile 64x64, one 16-MFMA cluster per K-tile).
// Reg-staged T14: issue next tile's 6 f32x4 at tile top, MFMA cluster
// (setprio), cvt+swizzled ds_write late (sched_barrier pins cvt after MFMAs).
// LDS pair-granule swizzle (0-conflict, r6+): pair p=row>>1 holds 8 granules
// (128B); logical g=(row&1)*4+slot; phys = g ^ (p&7). foff identical r6+.
__global__ __launch_bounds__(512, 2) void gemm_fused(
    const float* __restrict__ Wf, const float* __restrict__ uf,
    const float* __restrict__ bias, unsigned short* __restrict__ klin)
{
    __shared__ unsigned short As[2][256 * 32];   // 2 x 16 KB
    __shared__ unsigned short Bs[2][128 * 32];   // 2 x 8 KB

    // XCD-contiguous: XCD x gets wg in [64x,64x+64) = one whole batch;
    // h innermost: 4 consecutive wgs share one 512 KB u l-panel (L2-hot).
    int wg = (int)blockIdx.x;
    wg = (wg & 7) * 64 + (wg >> 3);
    const int b    = wg >> 6;
    const int rest = wg & 63;
    const int h0 = (rest & 3) * 256;
    const int l0 = (rest >> 2) * 128;
    const int tid = (int)threadIdx.x;
    const int lane = tid & 63, wv = tid >> 6;

    // A staging: row srA = tid>>1 (0..255), k-half hfA = tid&1 (16 f32)
    const int srA = tid >> 1, hfA = tid & 1;
    const int pA  = srA >> 1;
    const int gA0i = (srA & 1) * 4 + 2 * hfA;
    const int wA0 = pA * 128 + ((gA0i)     ^ (pA & 7)) * 16;
    const int wA1 = pA * 128 + ((gA0i + 1) ^ (pA & 7)) * 16;
    const float* gA = Wf + (size_t)(h0 + srA) * DM + hfA * 16;

    // B staging: row srB = tid>>2 (0..127), quarter qf = tid&3 (8 f32)
    const int srB = tid >> 2, qf = tid & 3;
    const int pB  = srB >> 1;
    const int gBi = (srB & 1) * 4 + qf;
    const int wB0 = pB * 128 + (gBi ^ (pB & 7)) * 16;
    const float* gB = uf + ((size_t)b * L_SEQ + l0 + srB) * DM + qf * 8;

    const int wm = wv >> 1, wn = wv & 1;     // 4M x 2N
    const int lr = lane & 15, lk = lane >> 4;
    const int foff = (lr >> 1) * 128 + ((((lr & 1) << 2) + lk) ^ (lr >> 1)) * 16;

    f32x4 acc[4][4];
    #pragma unroll
    for (int m = 0; m < 4; ++m)
        #pragma unroll
        for (int n = 0; n < 4; ++n) acc[m][n] = (f32x4){0.f, 0.f, 0.f, 0.f};

    {   // prologue: stage tile 0
        f32x4 a0 = *(const f32x4*)(gA),      a1 = *(const f32x4*)(gA + 4);
        f32x4 a2 = *(const f32x4*)(gA + 8),  a3 = *(const f32x4*)(gA + 12);
        f32x4 b0 = *(const f32x4*)(gB),      b1 = *(const f32x4*)(gB + 4);
        *(short8*)((char*)&As[0][0] + wA0) = pack8(a0, a1);
        *(short8*)((char*)&As[0][0] + wA1) = pack8(a2, a3);
        *(short8*)((char*)&Bs[0][0] + wB0) = pack8(b0, b1);
    }
    __syncthreads();

    #pragma unroll 1
    for (int t = 0; t < 32; ++t) {
        const int cur = t & 1;
        const char* Ab = (const char*)&As[cur][0];
        const char* Bb = (const char*)&Bs[cur][0];
        f32x4 a0, a1, a2, a3, b0, b1;
        if (t < 31) {   // issue next-tile loads early (T14 split)
            const int ko = (t + 1) * 32;
            a0 = *(const f32x4*)(gA + ko);     a1 = *(const f32x4*)(gA + ko + 4);
            a2 = *(const f32x4*)(gA + ko + 8); a3 = *(const f32x4*)(gA + ko + 12);
            b0 = *(const f32x4*)(gB + ko);     b1 = *(const f32x4*)(gB + ko + 4);
        }
        short8 af[4], bfr[4];
        #pragma unroll
        for (int nf = 0; nf < 4; ++nf)
            bfr[nf] = *(const short8*)(Bb + (wn * 64 + nf * 16) * 64 + foff);
        #pragma unroll
        for (int mf = 0; mf < 4; ++mf)
            af[mf] = *(const short8*)(Ab + (wm * 64 + mf * 16) * 64 + foff);
        __builtin_amdgcn_s_setprio(1);
        #pragma unroll
        for (int mf = 0; mf < 4; ++mf)
            #pragma unroll
            for (int nf = 0; nf < 4; ++nf)
                acc[mf][nf] = __builtin_amdgcn_mfma_f32_16x16x32_bf16(af[mf], bfr[nf], acc[mf][nf], 0, 0, 0);
        __builtin_amdgcn_s_setprio(0);
        __builtin_amdgcn_sched_barrier(0);   // keep cvt (and its vmcnt wait) after MFMAs
        if (t < 31) {   // write-late: cvt + swizzled ds_write into other buffer
            char* An = (char*)&As[cur ^ 1][0];
            char* Bn = (char*)&Bs[cur ^ 1][0];
            *(short8*)(An + wA0) = pack8(a0, a1);
            *(short8*)(An + wA1) = pack8(a2, a3);
            *(short8*)(Bn + wB0) = pack8(b0, b1);
            __syncthreads();
        }
    }

    // epilogue: D row=(lane>>4)*4+reg (h), col=lane&15 (l)
    #pragma unroll
    for (int mf = 0; mf < 4; ++mf) {
        const int h = h0 + wm * 64 + mf * 16 + lk * 4;
        #pragma unroll
        for (int nf = 0; nf < 4; ++nf) {
            const int l = l0 + wn * 64 + nf * 16 + lr;
            #pragma unroll
            for (int r = 0; r < 4; ++r) {
                float v = acc[mf][nf][r] + bias[h + r];
                klin[((size_t)b * DM + h + r) * L_SEQ + l] = f2bf(v);
            }
        }
    }
}

// ---------------- expand: one block per (h, b-pair); 29.7KB LDS (r12 version) ----
__device__ inline void get_disc(const float* __restrict__ log_dt,
                                const float* __restrict__ lar,
                                const float* __restrict__ aim, int h, int n,
                                float& Are, float& Aim, float& lre, float& lim)
{
    float dtv = expf(log_dt[h]);
    Are = -expf(lar[h * 64 + n]);
    Aim = aim[h * 64 + n];
    lre = dtv * Are;
    lim = dtv * Aim;
}

__global__ __launch_bounds__(256, 5) void expand(
    const unsigned short* __restrict__ klin,
    const float* __restrict__ shift_B, const float* __restrict__ shift_C,
    const float* __restrict__ ssm_k_D, const float* __restrict__ log_dt,
    const float* __restrict__ log_A_real, const float* __restrict__ A_imag,
    const float* __restrict__ B_re, const float* __restrict__ B_im,
    float* __restrict__ out)
{
    __shared__ __align__(16) char sm[29696];
    constexpr int OKL = 0;
    constexpr int OKK = 8704;
    constexpr int OAF = 16896;
    constexpr int OPR = 20224;
    constexpr int OPI = 24320;
    constexpr int OF  = 28416;
    constexpr int OBS = 28672;
    constexpr int OCS = 28928;
    constexpr int OW32 = 29184;

    const int h  = blockIdx.x;
    const int bg = blockIdx.y;
    const int t = threadIdx.x;
    const int lane = t & 63, wv = t >> 6;

    if (t < 32) {
        int rl = t >> 4, reg = (t >> 3) & 1, idx = t & 7;
        *(f32x4*)&sm[OKL + rl * 4352 + reg * 4224 + idx * 16] = (f32x4){0.f, 0.f, 0.f, 0.f};
    }
    {
        const int rl = wv >> 1, hf = wv & 1;
        const int b = bg * 2 + rl;
        const char* krow = (const char*)(klin + ((size_t)b * DM + h) * L_SEQ);
        const int s = (2 * rl + 1 + (lane >> 3)) & 7;
        const int so = hf * 2048 + (lane >> 3) * 128 + ((lane ^ s) & 7) * 16;
        gload_lds16(krow + so,        &sm[OKL + rl * 4352 + 128 + hf * 2048]);
        gload_lds16(krow + so + 1024, &sm[OKL + rl * 4352 + 128 + hf * 2048 + 1024]);
    }
    if (t < 64) {
        ((float*)&sm[OBS])[t] = shift_B[h * 64 + t];
        ((float*)&sm[OCS])[t] = shift_C[h * 64 + t];
        float Are, Aim, lre, lim;
        get_disc(log_dt, log_A_real, A_imag, h, t, Are, Aim, lre, lim);
        float er = expf(32.f * lre);
        float sn, cs; sincosf(32.f * lim, &sn, &cs);
        ((float*)&sm[OW32])[t * 2]     = er * cs;
        ((float*)&sm[OW32])[t * 2 + 1] = er * sn;
    }
    {
        int n = t >> 2, s4 = t & 3;
        float Are, Aim, lre, lim;
        get_disc(log_dt, log_A_real, A_imag, h, n, Are, Aim, lre, lim);
        float erw = expf(lre), snw, csw;
        sincosf(lim, &snw, &csw);
        float wr = erw * csw, wi = erw * snw;
        float e0 = (float)(24 - 8 * s4);
        float mag = expf(e0 * lre);
        float sn0, cs0; sincosf(e0 * lim, &sn0, &cs0);
        float pr = mag * cs0, pi = mag * sn0;
        float vr[8], vi[8];
        vr[7] = pr; vi[7] = pi;
        #pragma unroll
        for (int k = 6; k >= 0; --k) {
            float nr = pr * wr - pi * wi;
            pi = fmaf(pr, wi, pi * wr);
            pr = nr;
            vr[k] = pr; vi[k] = pi;
        }
        short8 re8, im8;
        #pragma unroll
        for (int e = 0; e < 8; ++e) {
            re8[e] = (short)f2bf(vr[e]);
            im8[e] = (short)f2bf(vi[e]);
        }
        *(short8*)&sm[OPR + t * 16] = re8;
        *(short8*)&sm[OPI + t * 16] = im8;
    }
    __syncthreads();   // B1

    if (t < 64) {
        const float* Bp = (const float*)&sm[OBS];
        const float* Cp = (const float*)&sm[OCS];
        float f = (t == 0) ? ssm_k_D[h] : 0.f;
        #pragma unroll 8
        for (int j = 0; j < 64; ++j) {
            float cv = Cp[(j + t) & 63];
            f = fmaf((j + t < 64) ? cv : 0.f, Bp[j], f);
        }
        ((float*)&sm[OF])[t] = f;
    }
    __syncthreads();   // B2

    {
        int i = t >> 4, ks = t & 15;
        if (ks < 12) {
            const float* Fp = (const float*)&sm[OF];
            short8 row;
            #pragma unroll
            for (int e = 0; e < 8; ++e) {
                int k = ks * 8 + e;
                int m = 64 + i - k;
                float v = (m >= 0 && m < 64) ? Fp[m] : 0.f;
                row[e] = (short)f2bf(v);
            }
            *(short8*)&sm[OAF + i * 208 + ks * 16] = row;
        }
    }
    __syncthreads();   // B3

    {
        short8 afr[3];
        #pragma unroll
        for (int ks = 0; ks < 3; ++ks)
            afr[ks] = *(const short8*)&sm[OAF + (lane & 15) * 208 + ks * 64 + (lane >> 4) * 16];
        const int rl = wv >> 1;
        const int jbase = (wv & 1) * 4;
        #pragma unroll
        for (int jj = 0; jj < 4; ++jj) {
            const int jg = jbase + jj;
            f32x4 d = (f32x4){0.f, 0.f, 0.f, 0.f};
            #pragma unroll
            for (int ks = 0; ks < 3; ++ks) {
                int o = rl * 4352 + (jg * 256 + (lane & 15) * 16 + ks * 32 + (lane >> 4) * 8) * 2;
                o ^= ((o >> 7) & 7) << 4;     // SWL
                short8 bfrag = *(const short8*)&sm[OKL + o];
                d = __builtin_amdgcn_mfma_f32_16x16x32_bf16(afr[ks], bfrag, d, 0, 0, 0);
            }
            unsigned pk0 = ((unsigned)f2bf(d[0])) | (((unsigned)f2bf(d[1])) << 16);
            unsigned pk1 = ((unsigned)f2bf(d[2])) | (((unsigned)f2bf(d[3])) << 16);
            int o2 = rl * 4096 + jg * 512 + (lane & 15) * 32 + (lane >> 4) * 8;
            o2 ^= ((o2 >> 9) & 7) << 4;       // SWK
            *(u32x2*)&sm[OKK + o2] = (u32x2){pk0, pk1};
        }
    }
    __syncthreads();   // B4

    {
        const int mt = wv;
        short8 par = *(const short8*)&sm[OPR + (mt * 16 + (lane & 15)) * 64 + (lane >> 4) * 16];
        short8 pai = *(const short8*)&sm[OPI + (mt * 16 + (lane & 15)) * 64 + (lane >> 4) * 16];
        float w32r[4], w32i[4];
        #pragma unroll
        for (int rg = 0; rg < 4; ++rg) {
            int n = mt * 16 + (lane >> 4) * 4 + rg;
            float2 ww = *(const float2*)&sm[OW32 + n * 8];
            w32r[rg] = ww.x;
            w32i[rg] = ww.y;
        }
        f32x4 cr = (f32x4){0.f, 0.f, 0.f, 0.f};
        f32x4 ci_ = (f32x4){0.f, 0.f, 0.f, 0.f};
        const int colb = (lane & 15) >> 3;
        const int colr = lane & 7;
        #pragma unroll
        for (int g2 = 0; g2 < 8; ++g2) {
            int o = colb * 4096 + colr * 512 + g2 * 64 + (lane >> 4) * 16;
            o ^= ((o >> 9) & 7) << 4;         // SWK
            short8 kf = *(const short8*)&sm[OKK + o];
            f32x4 sre = __builtin_amdgcn_mfma_f32_16x16x32_bf16(par, kf, (f32x4){0.f,0.f,0.f,0.f}, 0, 0, 0);
            f32x4 sim = __builtin_amdgcn_mfma_f32_16x16x32_bf16(pai, kf, (f32x4){0.f,0.f,0.f,0.f}, 0, 0, 0);
            #pragma unroll
            for (int rg = 0; rg < 4; ++rg) {
                float wr = w32r[rg], wi = w32i[rg];
                float ncr = fmaf(cr[rg], wr, fmaf(-ci_[rg], wi, sre[rg]));
                float nci = fmaf(cr[rg], wi, fmaf(ci_[rg], wr, sim[rg]));
                cr[rg] = ncr;
                ci_[rg] = nci;
            }
        }
        __syncthreads();   // B5
        #pragma unroll
        for (int rg = 0; rg < 4; ++rg) {
            int n = mt * 16 + (lane >> 4) * 4 + rg;
            int c = lane & 15;
            ((float*)&sm[OKK])[n * 17 + c] = cr[rg];
            ((float*)&sm[OKK])[1088 + n * 17 + c] = ci_[rg];
        }
    }
    __syncthreads();   // B6

    if (t < 128) {
        const int n = t & 63, bl = t >> 6;
        const int b = bg * 2 + bl;
        float Are, Aim, lre, lim;
        get_disc(log_dt, log_A_real, A_imag, h, n, Are, Aim, lre, lim);
        float er = expf(lre), sn, cs;
        sincosf(lim, &sn, &cs);
        float wr = er * cs, wi = er * sn;
        float2 w32v = *(const float2*)&sm[OW32 + n * 8];
        float ar = w32v.x, ai = w32v.y;
        #pragma unroll
        for (int s = 0; s < 3; ++s) {
            float nr = ar * ar - ai * ai;
            ai = 2.f * ar * ai;
            ar = nr;
        }
        float den = Are * Are + Aim * Aim;
        float wm1r = wr - 1.f, wm1i = wi;
        float tr_ = (wm1r * Are + wm1i * Aim) / den;
        float ti_ = (wm1i * Are - wm1r * Aim) / den;
        float br = B_re[h * 64 + n], bi = B_im[h * 64 + n];
        float dBr = br * tr_ - bi * ti_;
        float dBi = br * ti_ + bi * tr_;
        const float* cre = (const float*)&sm[OKK] + n * 17 + bl * 8;
        const float* cim = (const float*)&sm[OKK] + 1088 + n * 17 + bl * 8;
        float sr = 0.f, si_ = 0.f;
        #pragma unroll
        for (int r = 0; r < 8; ++r) {
            float nsr = fmaf(ar, sr, fmaf(-ai, si_, cre[r]));
            float nsi = fmaf(ar, si_, fmaf(ai, sr, cim[r]));
            sr = nsr; si_ = nsi;
            out[(((size_t)b * NREC + r) * DM + h) * 64 + n] = dBr * sr - dBi * si_;
        }
    }
}

extern "C" void kernel_launch(void* const* d_in, const int* in_sizes, int n_in,
                              void* d_out, int out_size, void* d_ws, size_t ws_size,
                              hipStream_t stream)
{
    const float* u       = (const float*)d_in[0];
    const float* W       = (const float*)d_in[1];
    const float* bias    = (const float*)d_in[2];
    const float* shift_B = (const float*)d_in[3];
    const float* shift_C = (const float*)d_in[4];
    const float* ssm_k_D = (const float*)d_in[5];
    const float* log_dt  = (const float*)d_in[6];
    const float* log_Ar  = (const float*)d_in[7];
    const float* A_imag  = (const float*)d_in[8];
    const float* B_re    = (const float*)d_in[9];
    const float* B_im    = (const float*)d_in[10];
    float* out = (float*)d_out;

    unsigned short* klin = (unsigned short*)d_ws;   // 32 MB

    gemm_fused<<<dim3(512), 512, 0, stream>>>(W, u, bias, klin);

    expand<<<dim3(DM, 4), 256, 0, stream>>>(klin, shift_B, shift_C, ssm_k_D, log_dt,
                                            log_Ar, A_imag, B_re, B_im, out);
}

// Round 14
// 86.677 us; speedup vs baseline: 1.1720x; 1.1720x over previous
//
#include <hip/hip_runtime.h>
#include <hip/hip_bf16.h>
#include <cstddef>
#include <cstdint>

#define L_SEQ 2048
#define DM    1024
#define NREC  8

typedef __attribute__((ext_vector_type(8))) short short8;
typedef __attribute__((ext_vector_type(4))) float f32x4;
typedef __attribute__((ext_vector_type(2))) unsigned int u32x2;

// native conversion: compiler fuses adjacent casts into v_cvt_pk_bf16_f32 (RNE)
__device__ inline unsigned short f2bf(float f) {
    __hip_bfloat16 h = __float2bfloat16(f);
    return __builtin_bit_cast(unsigned short, h);
}
__device__ inline void gload_lds16(const void* g, void* l) {
    __builtin_amdgcn_global_load_lds(
        (const __attribute__((address_space(1))) void*)g,
        (__attribute__((address_space(3))) void*)l, 16, 0, 0);
}
__device__ inline short8 pack8(f32x4 x, f32x4 y) {
    short8 c;
    c[0] = (short)f2bf(x[0]); c[1] = (short)f2bf(x[1]);
    c[2] = (short)f2bf(x[2]); c[3] = (short)f2bf(x[3]);
    c[4] = (short)f2bf(y[0]); c[5] = (short)f2bf(y[1]);
    c[6] = (short)f2bf(y[2]); c[7] = (short)f2bf(y[3]);
    return c;
}

// ---------------- W f32 -> bf16 (1M elems, ~1 us) ----------------
__global__ __launch_bounds__(256) void cvt_w(
    const float* __restrict__ in, unsigned short* __restrict__ out, int n)
{
    int i = (blockIdx.x * 256 + threadIdx.x) * 8;
    if (i >= n) return;
    f32x4 v0 = *(const f32x4*)(in + i);
    f32x4 v1 = *(const f32x4*)(in + i + 4);
    *(short8*)(out + i) = pack8(v0, v1);
}

// ======== hybrid 256x256 GEMM: klin[b][h][l] = W[h][:].u[b][l][:] + bias
// r12's exact allocator-stable configuration (512 thr, (512,2), grid 256,
// 2-deep 64KB LDS dbuf, 8 waves 2Mx4N, two 16-MFMA clusters per BK=32 tile)
// with the A-operand switched to global_load_lds from pre-converted Wb
// (r7's byte-identical proven source-swizzle algebra). B (u) keeps r12's
// reg-staged fused-cvt path. Deletes per thread/tile: 4 f32x4 A-loads,
// 16 cvt_pk, 2 ds_write_b128; staging regs 32 -> 16 (away from the sink
// threshold that collapsed r9/r10/r13).
// LDS pair-granule swizzle (0-conflict, r6+): pair p=row>>1 (rows are 64B)
// holds 8 granules of 16B (128B = all banks); logical g=(row&1)*4+slot;
// phys = g ^ (p&7). Fragment read foff byte-identical r6+.
__global__ __launch_bounds__(512, 2) void gemm_fused(
    const unsigned short* __restrict__ Wb, const float* __restrict__ uf,
    const float* __restrict__ bias, unsigned short* __restrict__ klin)
{
    __shared__ unsigned short As[2][256 * 32];   // 2 x 16 KB
    __shared__ unsigned short Bs[2][256 * 32];   // 2 x 16 KB

    // XCD-contiguous: XCD x gets wg in [32x,32x+32) = one whole batch.
    int wg = (int)blockIdx.x;
    wg = (wg & 7) * 32 + (wg >> 3);
    const int b  = wg >> 5;
    const int l0 = ((wg >> 2) & 7) * 256;
    const int h0 = (wg & 3) * 256;
    const int tid = (int)threadIdx.x;
    const int lane = tid & 63, wv = tid >> 6;

    // ---- A staging via gload_lds (r7-verbatim geometry) ----
    // instr j of wave wv covers rows [wv*16 + 128*j, +16); lane writes phys
    // granule lane&7 at pair wv*8+(lane>>3) -> logical g = (lane&7)^(lane>>3)
    const int l3 = lane >> 3, l7 = lane & 7;
    const int gsw  = l7 ^ l3;
    const int rij  = l3 * 2 + (gsw >> 2);
    const int kcol = (gsw & 3) * 8;
    const int rA0  = wv * 16 + rij;
    const unsigned short* gA0b = Wb + (size_t)(h0 + rA0) * DM + kcol;
    const unsigned short* gA1b = gA0b + (size_t)128 * DM;
    const int dstA0 = (wv * 8) * 128;         // byte offset (rows wv*16..)
    const int dstA1 = (64 + wv * 8) * 128;    // rows 128+wv*16..

    // ---- B staging (r12-verbatim reg-staged fused cvt) ----
    const int sr0  = tid >> 2;        // 0..127
    const int slot = tid & 3;
    const int sr1  = sr0 + 128;
    const float* gB0 = uf + ((size_t)b * L_SEQ + l0 + sr0) * DM + slot * 8;
    const float* gB1 = uf + ((size_t)b * L_SEQ + l0 + sr1) * DM + slot * 8;
    const int w0off = (sr0 >> 1) * 128 + ((((sr0 & 1) << 2) + slot) ^ ((sr0 >> 1) & 7)) * 16;
    const int w1off = (sr1 >> 1) * 128 + ((((sr1 & 1) << 2) + slot) ^ ((sr1 >> 1) & 7)) * 16;

    const int wm = wv >> 2, wn = wv & 3;
    const int lr = lane & 15, lk = lane >> 4;
    const int foff = (lr >> 1) * 128 + ((((lr & 1) << 2) + lk) ^ (lr >> 1)) * 16;

    f32x4 acc[8][4];
    #pragma unroll
    for (int mf = 0; mf < 8; ++mf)
        #pragma unroll
        for (int nf = 0; nf < 4; ++nf) acc[mf][nf] = (f32x4){0.f, 0.f, 0.f, 0.f};

    {   // prologue: stage tile 0
        gload_lds16(gA0b, (char*)&As[0][0] + dstA0);
        gload_lds16(gA1b, (char*)&As[0][0] + dstA1);
        f32x4 b0 = *(const f32x4*)(gB0), b1 = *(const f32x4*)(gB0 + 4);
        f32x4 b2 = *(const f32x4*)(gB1), b3 = *(const f32x4*)(gB1 + 4);
        *(short8*)((char*)&Bs[0][0] + w0off) = pack8(b0, b1);
        *(short8*)((char*)&Bs[0][0] + w1off) = pack8(b2, b3);
    }
    __syncthreads();

    #pragma unroll 1
    for (int t = 0; t < 32; ++t) {
        const int cur = t & 1;
        const char* Ab = (const char*)&As[cur][0];
        const char* Bb = (const char*)&Bs[cur][0];
        f32x4 b0, b1, b2, b3;
        if (t < 31) {   // issue next-tile loads early (T14 split)
            const int ko = (t + 1) * 32;
            gload_lds16(gA0b + ko, (char*)&As[cur ^ 1][0] + dstA0);
            gload_lds16(gA1b + ko, (char*)&As[cur ^ 1][0] + dstA1);
            b0 = *(const f32x4*)(gB0 + ko); b1 = *(const f32x4*)(gB0 + ko + 4);
            b2 = *(const f32x4*)(gB1 + ko); b3 = *(const f32x4*)(gB1 + ko + 4);
        }
        short8 af[4], bfr[4];
        // ---- phase 0: B frags + A mf0-3, 16 MFMA ----
        #pragma unroll
        for (int nf = 0; nf < 4; ++nf)
            bfr[nf] = *(const short8*)(Bb + (wn * 64 + nf * 16) * 64 + foff);
        #pragma unroll
        for (int mf = 0; mf < 4; ++mf)
            af[mf] = *(const short8*)(Ab + (wm * 128 + mf * 16) * 64 + foff);
        __builtin_amdgcn_s_setprio(1);
        #pragma unroll
        for (int mf = 0; mf < 4; ++mf)
            #pragma unroll
            for (int nf = 0; nf < 4; ++nf)
                acc[mf][nf] = __builtin_amdgcn_mfma_f32_16x16x32_bf16(af[mf], bfr[nf], acc[mf][nf], 0, 0, 0);
        __builtin_amdgcn_s_setprio(0);
        // ---- phase 1: A mf4-7 (reuse B frags), 16 MFMA ----
        #pragma unroll
        for (int mf = 0; mf < 4; ++mf)
            af[mf] = *(const short8*)(Ab + (wm * 128 + (mf + 4) * 16) * 64 + foff);
        __builtin_amdgcn_s_setprio(1);
        #pragma unroll
        for (int mf = 0; mf < 4; ++mf)
            #pragma unroll
            for (int nf = 0; nf < 4; ++nf)
                acc[mf + 4][nf] = __builtin_amdgcn_mfma_f32_16x16x32_bf16(af[mf], bfr[nf], acc[mf + 4][nf], 0, 0, 0);
        __builtin_amdgcn_s_setprio(0);
        __builtin_amdgcn_sched_barrier(0);   // keep B-cvt (and its vmcnt wait) after MFMAs
        // ---- write-late: cvt + swizzled ds_write of B into the other buffer ----
        if (t < 31) {
            char* Bn = (char*)&Bs[cur ^ 1][0];
            *(short8*)(Bn + w0off) = pack8(b0, b1);
            *(short8*)(Bn + w1off) = pack8(b2, b3);
            __syncthreads();
        }
    }

    // epilogue: D row=(lane>>4)*4+reg (h), col=lane&15 (l)
    #pragma unroll
    for (int mf = 0; mf < 8; ++mf) {
        const int h = h0 + wm * 128 + mf * 16 + lk * 4;
        #pragma unroll
        for (int nf = 0; nf < 4; ++nf) {
            const int l = l0 + wn * 64 + nf * 16 + lr;
            #pragma unroll
            for (int r = 0; r < 4; ++r) {
                float v = acc[mf][nf][r] + bias[h + r];
                klin[((size_t)b * DM + h + r) * L_SEQ + l] = f2bf(v);
            }
        }
    }
}

// ---------------- expand: one block per (h, b-pair); 29.7KB LDS (r12 version) ----
__device__ inline void get_disc(const float* __restrict__ log_dt,
                                const float* __restrict__ lar,
                                const float* __restrict__ aim, int h, int n,
                                float& Are, float& Aim, float& lre, float& lim)
{
    float dtv = expf(log_dt[h]);
    Are = -expf(lar[h * 64 + n]);
    Aim = aim[h * 64 + n];
    lre = dtv * Are;
    lim = dtv * Aim;
}

__global__ __launch_bounds__(256, 5) void expand(
    const unsigned short* __restrict__ klin,
    const float* __restrict__ shift_B, const float* __restrict__ shift_C,
    const float* __restrict__ ssm_k_D, const float* __restrict__ log_dt,
    const float* __restrict__ log_A_real, const float* __restrict__ A_imag,
    const float* __restrict__ B_re, const float* __restrict__ B_im,
    float* __restrict__ out)
{
    __shared__ __align__(16) char sm[29696];
    constexpr int OKL = 0;
    constexpr int OKK = 8704;
    constexpr int OAF = 16896;
    constexpr int OPR = 20224;
    constexpr int OPI = 24320;
    constexpr int OF  = 28416;
    constexpr int OBS = 28672;
    constexpr int OCS = 28928;
    constexpr int OW32 = 29184;

    const int h  = blockIdx.x;
    const int bg = blockIdx.y;
    const int t = threadIdx.x;
    const int lane = t & 63, wv = t >> 6;

    if (t < 32) {
        int rl = t >> 4, reg = (t >> 3) & 1, idx = t & 7;
        *(f32x4*)&sm[OKL + rl * 4352 + reg * 4224 + idx * 16] = (f32x4){0.f, 0.f, 0.f, 0.f};
    }
    {
        const int rl = wv >> 1, hf = wv & 1;
        const int b = bg * 2 + rl;
        const char* krow = (const char*)(klin + ((size_t)b * DM + h) * L_SEQ);
        const int s = (2 * rl + 1 + (lane >> 3)) & 7;
        const int so = hf * 2048 + (lane >> 3) * 128 + ((lane ^ s) & 7) * 16;
        gload_lds16(krow + so,        &sm[OKL + rl * 4352 + 128 + hf * 2048]);
        gload_lds16(krow + so + 1024, &sm[OKL + rl * 4352 + 128 + hf * 2048 + 1024]);
    }
    if (t < 64) {
        ((float*)&sm[OBS])[t] = shift_B[h * 64 + t];
        ((float*)&sm[OCS])[t] = shift_C[h * 64 + t];
        float Are, Aim, lre, lim;
        get_disc(log_dt, log_A_real, A_imag, h, t, Are, Aim, lre, lim);
        float er = expf(32.f * lre);
        float sn, cs; sincosf(32.f * lim, &sn, &cs);
        ((float*)&sm[OW32])[t * 2]     = er * cs;
        ((float*)&sm[OW32])[t * 2 + 1] = er * sn;
    }
    {
        int n = t >> 2, s4 = t & 3;
        float Are, Aim, lre, lim;
        get_disc(log_dt, log_A_real, A_imag, h, n, Are, Aim, lre, lim);
        float erw = expf(lre), snw, csw;
        sincosf(lim, &snw, &csw);
        float wr = erw * csw, wi = erw * snw;
        float e0 = (float)(24 - 8 * s4);
        float mag = expf(e0 * lre);
        float sn0, cs0; sincosf(e0 * lim, &sn0, &cs0);
        float pr = mag * cs0, pi = mag * sn0;
        float vr[8], vi[8];
        vr[7] = pr; vi[7] = pi;
        #pragma unroll
        for (int k = 6; k >= 0; --k) {
            float nr = pr * wr - pi * wi;
            pi = fmaf(pr, wi, pi * wr);
            pr = nr;
            vr[k] = pr; vi[k] = pi;
        }
        short8 re8, im8;
        #pragma unroll
        for (int e = 0; e < 8; ++e) {
            re8[e] = (short)f2bf(vr[e]);
            im8[e] = (short)f2bf(vi[e]);
        }
        *(short8*)&sm[OPR + t * 16] = re8;
        *(short8*)&sm[OPI + t * 16] = im8;
    }
    __syncthreads();   // B1

    if (t < 64) {
        const float* Bp = (const float*)&sm[OBS];
        const float* Cp = (const float*)&sm[OCS];
        float f = (t == 0) ? ssm_k_D[h] : 0.f;
        #pragma unroll 8
        for (int j = 0; j < 64; ++j) {
            float cv = Cp[(j + t) & 63];
            f = fmaf((j + t < 64) ? cv : 0.f, Bp[j], f);
        }
        ((float*)&sm[OF])[t] = f;
    }
    __syncthreads();   // B2

    {
        int i = t >> 4, ks = t & 15;
        if (ks < 12) {
            const float* Fp = (const float*)&sm[OF];
            short8 row;
            #pragma unroll
            for (int e = 0; e < 8; ++e) {
                int k = ks * 8 + e;
                int m = 64 + i - k;
                float v = (m >= 0 && m < 64) ? Fp[m] : 0.f;
                row[e] = (short)f2bf(v);
            }
            *(short8*)&sm[OAF + i * 208 + ks * 16] = row;
        }
    }
    __syncthreads();   // B3

    {
        short8 afr[3];
        #pragma unroll
        for (int ks = 0; ks < 3; ++ks)
            afr[ks] = *(const short8*)&sm[OAF + (lane & 15) * 208 + ks * 64 + (lane >> 4) * 16];
        const int rl = wv >> 1;
        const int jbase = (wv & 1) * 4;
        #pragma unroll
        for (int jj = 0; jj < 4; ++jj) {
            const int jg = jbase + jj;
            f32x4 d = (f32x4){0.f, 0.f, 0.f, 0.f};
            #pragma unroll
            for (int ks = 0; ks < 3; ++ks) {
                int o = rl * 4352 + (jg * 256 + (lane & 15) * 16 + ks * 32 + (lane >> 4) * 8) * 2;
                o ^= ((o >> 7) & 7) << 4;     // SWL
                short8 bfrag = *(const short8*)&sm[OKL + o];
                d = __builtin_amdgcn_mfma_f32_16x16x32_bf16(afr[ks], bfrag, d, 0, 0, 0);
            }
            unsigned pk0 = ((unsigned)f2bf(d[0])) | (((unsigned)f2bf(d[1])) << 16);
            unsigned pk1 = ((unsigned)f2bf(d[2])) | (((unsigned)f2bf(d[3])) << 16);
            int o2 = rl * 4096 + jg * 512 + (lane & 15) * 32 + (lane >> 4) * 8;
            o2 ^= ((o2 >> 9) & 7) << 4;       // SWK
            *(u32x2*)&sm[OKK + o2] = (u32x2){pk0, pk1};
        }
    }
    __syncthreads();   // B4

    {
        const int mt = wv;
        short8 par = *(const short8*)&sm[OPR + (mt * 16 + (lane & 15)) * 64 + (lane >> 4) * 16];
        short8 pai = *(const short8*)&sm[OPI + (mt * 16 + (lane & 15)) * 64 + (lane >> 4) * 16];
        float w32r[4], w32i[4];
        #pragma unroll
        for (int rg = 0; rg < 4; ++rg) {
            int n = mt * 16 + (lane >> 4) * 4 + rg;
            float2 ww = *(const float2*)&sm[OW32 + n * 8];
            w32r[rg] = ww.x;
            w32i[rg] = ww.y;
        }
        f32x4 cr = (f32x4){0.f, 0.f, 0.f, 0.f};
        f32x4 ci_ = (f32x4){0.f, 0.f, 0.f, 0.f};
        const int colb = (lane & 15) >> 3;
        const int colr = lane & 7;
        #pragma unroll
        for (int g2 = 0; g2 < 8; ++g2) {
            int o = colb * 4096 + colr * 512 + g2 * 64 + (lane >> 4) * 16;
            o ^= ((o >> 9) & 7) << 4;         // SWK
            short8 kf = *(const short8*)&sm[OKK + o];
            f32x4 sre = __builtin_amdgcn_mfma_f32_16x16x32_bf16(par, kf, (f32x4){0.f,0.f,0.f,0.f}, 0, 0, 0);
            f32x4 sim = __builtin_amdgcn_mfma_f32_16x16x32_bf16(pai, kf, (f32x4){0.f,0.f,0.f,0.f}, 0, 0, 0);
            #pragma unroll
            for (int rg = 0; rg < 4; ++rg) {
                float wr = w32r[rg], wi = w32i[rg];
                float ncr = fmaf(cr[rg], wr, fmaf(-ci_[rg], wi, sre[rg]));
                float nci = fmaf(cr[rg], wi, fmaf(ci_[rg], wr, sim[rg]));
                cr[rg] = ncr;
                ci_[rg] = nci;
            }
        }
        __syncthreads();   // B5
        #pragma unroll
        for (int rg = 0; rg < 4; ++rg) {
            int n = mt * 16 + (lane >> 4) * 4 + rg;
            int c = lane & 15;
            ((float*)&sm[OKK])[n * 17 + c] = cr[rg];
            ((float*)&sm[OKK])[1088 + n * 17 + c] = ci_[rg];
        }
    }
    __syncthreads();   // B6

    if (t < 128) {
        const int n = t & 63, bl = t >> 6;
        const int b = bg * 2 + bl;
        float Are, Aim, lre, lim;
        get_disc(log_dt, log_A_real, A_imag, h, n, Are, Aim, lre, lim);
        float er = expf(lre), sn, cs;
        sincosf(lim, &sn, &cs);
        float wr = er * cs, wi = er * sn;
        float2 w32v = *(const float2*)&sm[OW32 + n * 8];
        float ar = w32v.x, ai = w32v.y;
        #pragma unroll
        for (int s = 0; s < 3; ++s) {
            float nr = ar * ar - ai * ai;
            ai = 2.f * ar * ai;
            ar = nr;
        }
        float den = Are * Are + Aim * Aim;
        float wm1r = wr - 1.f, wm1i = wi;
        float tr_ = (wm1r * Are + wm1i * Aim) / den;
        float ti_ = (wm1i * Are - wm1r * Aim) / den;
        float br = B_re[h * 64 + n], bi = B_im[h * 64 + n];
        float dBr = br * tr_ - bi * ti_;
        float dBi = br * ti_ + bi * tr_;
        const float* cre = (const float*)&sm[OKK] + n * 17 + bl * 8;
        const float* cim = (const float*)&sm[OKK] + 1088 + n * 17 + bl * 8;
        float sr = 0.f, si_ = 0.f;
        #pragma unroll
        for (int r = 0; r < 8; ++r) {
            float nsr = fmaf(ar, sr, fmaf(-ai, si_, cre[r]));
            float nsi = fmaf(ar, si_, fmaf(ai, sr, cim[r]));
            sr = nsr; si_ = nsi;
            out[(((size_t)b * NREC + r) * DM + h) * 64 + n] = dBr * sr - dBi * si_;
        }
    }
}

extern "C" void kernel_launch(void* const* d_in, const int* in_sizes, int n_in,
                              void* d_out, int out_size, void* d_ws, size_t ws_size,
                              hipStream_t stream)
{
    const float* u       = (const float*)d_in[0];
    const float* W       = (const float*)d_in[1];
    const float* bias    = (const float*)d_in[2];
    const float* shift_B = (const float*)d_in[3];
    const float* shift_C = (const float*)d_in[4];
    const float* ssm_k_D = (const float*)d_in[5];
    const float* log_dt  = (const float*)d_in[6];
    const float* log_Ar  = (const float*)d_in[7];
    const float* A_imag  = (const float*)d_in[8];
    const float* B_re    = (const float*)d_in[9];
    const float* B_im    = (const float*)d_in[10];
    float* out = (float*)d_out;

    unsigned short* klin = (unsigned short*)d_ws;                 // 32 MB
    unsigned short* Wb   = klin + (size_t)8 * L_SEQ * DM;         // +2 MB

    const int n_w = DM * DM;
    cvt_w<<<n_w / (256 * 8), 256, 0, stream>>>(W, Wb, n_w);

    gemm_fused<<<dim3(256), 512, 0, stream>>>(Wb, u, bias, klin);

    expand<<<dim3(DM, 4), 256, 0, stream>>>(klin, shift_B, shift_C, ssm_k_D, log_dt,
                                            log_Ar, A_imag, B_re, B_im, out);
}

// Round 15
// 74.316 us; speedup vs baseline: 1.3670x; 1.1663x over previous
//
#include <hip/hip_runtime.h>
#include <hip/hip_bf16.h>
#include <cstddef>
#include <cstdint>

#define L_SEQ 2048
#define DM    1024
#define NREC  8

typedef __attribute__((ext_vector_type(8))) short short8;
typedef __attribute__((ext_vector_type(4))) float f32x4;
typedef __attribute__((ext_vector_type(2))) unsigned int u32x2;

// native conversion: compiler fuses adjacent casts into v_cvt_pk_bf16_f32 (RNE)
__device__ inline unsigned short f2bf(float f) {
    __hip_bfloat16 h = __float2bfloat16(f);
    return __builtin_bit_cast(unsigned short, h);
}
__device__ inline void gload_lds16(const void* g, void* l) {
    __builtin_amdgcn_global_load_lds(
        (const __attribute__((address_space(1))) void*)g,
        (__attribute__((address_space(3))) void*)l, 16, 0, 0);
}
__device__ inline short8 pack8(f32x4 x, f32x4 y) {
    short8 c;
    c[0] = (short)f2bf(x[0]); c[1] = (short)f2bf(x[1]);
    c[2] = (short)f2bf(x[2]); c[3] = (short)f2bf(x[3]);
    c[4] = (short)f2bf(y[0]); c[5] = (short)f2bf(y[1]);
    c[6] = (short)f2bf(y[2]); c[7] = (short)f2bf(y[3]);
    return c;
}

// ======== fused-cvt 256x256 GEMM (r12 configuration — session best, 74.2 us)
// klin[b][h][l] = W[h][:].u[b][l][:] + bias.  8 waves (2M x 4N), BK=32,
// 2-deep LDS dbuf (64 KB), reg-staged T14: issue next tile's 8 f32x4 at tile
// top, 2 MFMA clusters (setprio), then cvt+swizzled ds_write late.
// LDS pair-granule swizzle (0-conflict, r6+): pair p=row>>1 holds 8 granules
// (128B); logical g=(row&1)*4+slot; phys = g ^ (p&7).
// NOTE: this exact configuration (512 thr, launch_bounds(512,2), grid 256,
// 8-load staging, VGPR 104) is the only allocator-stable point found —
// r9/r10/r13/r14 perturbations all sank the staged loads or added drains.
__global__ __launch_bounds__(512, 2) void gemm_fused(
    const float* __restrict__ Wf, const float* __restrict__ uf,
    const float* __restrict__ bias, unsigned short* __restrict__ klin)
{
    __shared__ unsigned short As[2][256 * 32];   // 2 x 16 KB
    __shared__ unsigned short Bs[2][256 * 32];   // 2 x 16 KB

    // XCD-contiguous: XCD x gets wg in [32x,32x+32) = one whole batch.
    int wg = (int)blockIdx.x;
    wg = (wg & 7) * 32 + (wg >> 3);
    const int b  = wg >> 5;
    const int l0 = ((wg >> 2) & 7) * 256;
    const int h0 = (wg & 3) * 256;
    const int tid = (int)threadIdx.x;
    const int lane = tid & 63, wv = tid >> 6;

    const int sr0  = tid >> 2;        // 0..127
    const int slot = tid & 3;
    const int sr1  = sr0 + 128;
    const float* gA0 = Wf + (size_t)(h0 + sr0) * DM + slot * 8;
    const float* gA1 = Wf + (size_t)(h0 + sr1) * DM + slot * 8;
    const float* gB0 = uf + ((size_t)b * L_SEQ + l0 + sr0) * DM + slot * 8;
    const float* gB1 = uf + ((size_t)b * L_SEQ + l0 + sr1) * DM + slot * 8;
    const int w0off = (sr0 >> 1) * 128 + ((((sr0 & 1) << 2) + slot) ^ ((sr0 >> 1) & 7)) * 16;
    const int w1off = (sr1 >> 1) * 128 + ((((sr1 & 1) << 2) + slot) ^ ((sr1 >> 1) & 7)) * 16;

    const int wm = wv >> 2, wn = wv & 3;
    const int lr = lane & 15, lk = lane >> 4;
    const int foff = (lr >> 1) * 128 + ((((lr & 1) << 2) + lk) ^ (lr >> 1)) * 16;

    f32x4 acc[8][4];
    #pragma unroll
    for (int mf = 0; mf < 8; ++mf)
        #pragma unroll
        for (int nf = 0; nf < 4; ++nf) acc[mf][nf] = (f32x4){0.f, 0.f, 0.f, 0.f};

    {   // prologue: stage tile 0
        f32x4 a0 = *(const f32x4*)(gA0), a1 = *(const f32x4*)(gA0 + 4);
        f32x4 a2 = *(const f32x4*)(gA1), a3 = *(const f32x4*)(gA1 + 4);
        f32x4 b0 = *(const f32x4*)(gB0), b1 = *(const f32x4*)(gB0 + 4);
        f32x4 b2 = *(const f32x4*)(gB1), b3 = *(const f32x4*)(gB1 + 4);
        *(short8*)((char*)&As[0][0] + w0off) = pack8(a0, a1);
        *(short8*)((char*)&As[0][0] + w1off) = pack8(a2, a3);
        *(short8*)((char*)&Bs[0][0] + w0off) = pack8(b0, b1);
        *(short8*)((char*)&Bs[0][0] + w1off) = pack8(b2, b3);
    }
    __syncthreads();

    #pragma unroll 1
    for (int t = 0; t < 32; ++t) {
        const int cur = t & 1;
        const char* Ab = (const char*)&As[cur][0];
        const char* Bb = (const char*)&Bs[cur][0];
        f32x4 a0, a1, a2, a3, b0, b1, b2, b3;
        if (t < 31) {   // issue next-tile loads early (T14 split)
            const int ko = (t + 1) * 32;
            a0 = *(const f32x4*)(gA0 + ko); a1 = *(const f32x4*)(gA0 + ko + 4);
            a2 = *(const f32x4*)(gA1 + ko); a3 = *(const f32x4*)(gA1 + ko + 4);
            b0 = *(const f32x4*)(gB0 + ko); b1 = *(const f32x4*)(gB0 + ko + 4);
            b2 = *(const f32x4*)(gB1 + ko); b3 = *(const f32x4*)(gB1 + ko + 4);
        }
        short8 af[4], bfr[4];
        // ---- phase 0: B frags + A mf0-3, 16 MFMA ----
        #pragma unroll
        for (int nf = 0; nf < 4; ++nf)
            bfr[nf] = *(const short8*)(Bb + (wn * 64 + nf * 16) * 64 + foff);
        #pragma unroll
        for (int mf = 0; mf < 4; ++mf)
            af[mf] = *(const short8*)(Ab + (wm * 128 + mf * 16) * 64 + foff);
        __builtin_amdgcn_s_setprio(1);
        #pragma unroll
        for (int mf = 0; mf < 4; ++mf)
            #pragma unroll
            for (int nf = 0; nf < 4; ++nf)
                acc[mf][nf] = __builtin_amdgcn_mfma_f32_16x16x32_bf16(af[mf], bfr[nf], acc[mf][nf], 0, 0, 0);
        __builtin_amdgcn_s_setprio(0);
        // ---- phase 1: A mf4-7 (reuse B frags), 16 MFMA ----
        #pragma unroll
        for (int mf = 0; mf < 4; ++mf)
            af[mf] = *(const short8*)(Ab + (wm * 128 + (mf + 4) * 16) * 64 + foff);
        __builtin_amdgcn_s_setprio(1);
        #pragma unroll
        for (int mf = 0; mf < 4; ++mf)
            #pragma unroll
            for (int nf = 0; nf < 4; ++nf)
                acc[mf + 4][nf] = __builtin_amdgcn_mfma_f32_16x16x32_bf16(af[mf], bfr[nf], acc[mf + 4][nf], 0, 0, 0);
        __builtin_amdgcn_s_setprio(0);
        __builtin_amdgcn_sched_barrier(0);   // keep cvt (and its vmcnt wait) after MFMAs
        // ---- write-late: cvt + swizzled ds_write into the other buffer ----
        if (t < 31) {
            char* An = (char*)&As[cur ^ 1][0];
            char* Bn = (char*)&Bs[cur ^ 1][0];
            *(short8*)(An + w0off) = pack8(a0, a1);
            *(short8*)(An + w1off) = pack8(a2, a3);
            *(short8*)(Bn + w0off) = pack8(b0, b1);
            *(short8*)(Bn + w1off) = pack8(b2, b3);
            __syncthreads();
        }
    }

    // epilogue: D row=(lane>>4)*4+reg (h), col=lane&15 (l)
    #pragma unroll
    for (int mf = 0; mf < 8; ++mf) {
        const int h = h0 + wm * 128 + mf * 16 + lk * 4;
        #pragma unroll
        for (int nf = 0; nf < 4; ++nf) {
            const int l = l0 + wn * 64 + nf * 16 + lr;
            #pragma unroll
            for (int r = 0; r < 4; ++r) {
                float v = acc[mf][nf][r] + bias[h + r];
                klin[((size_t)b * DM + h + r) * L_SEQ + l] = f2bf(v);
            }
        }
    }
}

// ---------------- expand: one block per (h, b-pair); 29.7KB LDS (r12 version) ----
__device__ inline void get_disc(const float* __restrict__ log_dt,
                                const float* __restrict__ lar,
                                const float* __restrict__ aim, int h, int n,
                                float& Are, float& Aim, float& lre, float& lim)
{
    float dtv = expf(log_dt[h]);
    Are = -expf(lar[h * 64 + n]);
    Aim = aim[h * 64 + n];
    lre = dtv * Are;
    lim = dtv * Aim;
}

__global__ __launch_bounds__(256, 5) void expand(
    const unsigned short* __restrict__ klin,
    const float* __restrict__ shift_B, const float* __restrict__ shift_C,
    const float* __restrict__ ssm_k_D, const float* __restrict__ log_dt,
    const float* __restrict__ log_A_real, const float* __restrict__ A_imag,
    const float* __restrict__ B_re, const float* __restrict__ B_im,
    float* __restrict__ out)
{
    __shared__ __align__(16) char sm[29696];
    constexpr int OKL = 0;
    constexpr int OKK = 8704;
    constexpr int OAF = 16896;
    constexpr int OPR = 20224;
    constexpr int OPI = 24320;
    constexpr int OF  = 28416;
    constexpr int OBS = 28672;
    constexpr int OCS = 28928;
    constexpr int OW32 = 29184;

    const int h  = blockIdx.x;
    const int bg = blockIdx.y;
    const int t = threadIdx.x;
    const int lane = t & 63, wv = t >> 6;

    if (t < 32) {
        int rl = t >> 4, reg = (t >> 3) & 1, idx = t & 7;
        *(f32x4*)&sm[OKL + rl * 4352 + reg * 4224 + idx * 16] = (f32x4){0.f, 0.f, 0.f, 0.f};
    }
    {
        const int rl = wv >> 1, hf = wv & 1;
        const int b = bg * 2 + rl;
        const char* krow = (const char*)(klin + ((size_t)b * DM + h) * L_SEQ);
        const int s = (2 * rl + 1 + (lane >> 3)) & 7;
        const int so = hf * 2048 + (lane >> 3) * 128 + ((lane ^ s) & 7) * 16;
        gload_lds16(krow + so,        &sm[OKL + rl * 4352 + 128 + hf * 2048]);
        gload_lds16(krow + so + 1024, &sm[OKL + rl * 4352 + 128 + hf * 2048 + 1024]);
    }
    if (t < 64) {
        ((float*)&sm[OBS])[t] = shift_B[h * 64 + t];
        ((float*)&sm[OCS])[t] = shift_C[h * 64 + t];
        float Are, Aim, lre, lim;
        get_disc(log_dt, log_A_real, A_imag, h, t, Are, Aim, lre, lim);
        float er = expf(32.f * lre);
        float sn, cs; sincosf(32.f * lim, &sn, &cs);
        ((float*)&sm[OW32])[t * 2]     = er * cs;
        ((float*)&sm[OW32])[t * 2 + 1] = er * sn;
    }
    {
        int n = t >> 2, s4 = t & 3;
        float Are, Aim, lre, lim;
        get_disc(log_dt, log_A_real, A_imag, h, n, Are, Aim, lre, lim);
        float erw = expf(lre), snw, csw;
        sincosf(lim, &snw, &csw);
        float wr = erw * csw, wi = erw * snw;
        float e0 = (float)(24 - 8 * s4);
        float mag = expf(e0 * lre);
        float sn0, cs0; sincosf(e0 * lim, &sn0, &cs0);
        float pr = mag * cs0, pi = mag * sn0;
        float vr[8], vi[8];
        vr[7] = pr; vi[7] = pi;
        #pragma unroll
        for (int k = 6; k >= 0; --k) {
            float nr = pr * wr - pi * wi;
            pi = fmaf(pr, wi, pi * wr);
            pr = nr;
            vr[k] = pr; vi[k] = pi;
        }
        short8 re8, im8;
        #pragma unroll
        for (int e = 0; e < 8; ++e) {
            re8[e] = (short)f2bf(vr[e]);
            im8[e] = (short)f2bf(vi[e]);
        }
        *(short8*)&sm[OPR + t * 16] = re8;
        *(short8*)&sm[OPI + t * 16] = im8;
    }
    __syncthreads();   // B1

    if (t < 64) {
        const float* Bp = (const float*)&sm[OBS];
        const float* Cp = (const float*)&sm[OCS];
        float f = (t == 0) ? ssm_k_D[h] : 0.f;
        #pragma unroll 8
        for (int j = 0; j < 64; ++j) {
            float cv = Cp[(j + t) & 63];
            f = fmaf((j + t < 64) ? cv : 0.f, Bp[j], f);
        }
        ((float*)&sm[OF])[t] = f;
    }
    __syncthreads();   // B2

    {
        int i = t >> 4, ks = t & 15;
        if (ks < 12) {
            const float* Fp = (const float*)&sm[OF];
            short8 row;
            #pragma unroll
            for (int e = 0; e < 8; ++e) {
                int k = ks * 8 + e;
                int m = 64 + i - k;
                float v = (m >= 0 && m < 64) ? Fp[m] : 0.f;
                row[e] = (short)f2bf(v);
            }
            *(short8*)&sm[OAF + i * 208 + ks * 16] = row;
        }
    }
    __syncthreads();   // B3

    {
        short8 afr[3];
        #pragma unroll
        for (int ks = 0; ks < 3; ++ks)
            afr[ks] = *(const short8*)&sm[OAF + (lane & 15) * 208 + ks * 64 + (lane >> 4) * 16];
        const int rl = wv >> 1;
        const int jbase = (wv & 1) * 4;
        #pragma unroll
        for (int jj = 0; jj < 4; ++jj) {
            const int jg = jbase + jj;
            f32x4 d = (f32x4){0.f, 0.f, 0.f, 0.f};
            #pragma unroll
            for (int ks = 0; ks < 3; ++ks) {
                int o = rl * 4352 + (jg * 256 + (lane & 15) * 16 + ks * 32 + (lane >> 4) * 8) * 2;
                o ^= ((o >> 7) & 7) << 4;     // SWL
                short8 bfrag = *(const short8*)&sm[OKL + o];
                d = __builtin_amdgcn_mfma_f32_16x16x32_bf16(afr[ks], bfrag, d, 0, 0, 0);
            }
            unsigned pk0 = ((unsigned)f2bf(d[0])) | (((unsigned)f2bf(d[1])) << 16);
            unsigned pk1 = ((unsigned)f2bf(d[2])) | (((unsigned)f2bf(d[3])) << 16);
            int o2 = rl * 4096 + jg * 512 + (lane & 15) * 32 + (lane >> 4) * 8;
            o2 ^= ((o2 >> 9) & 7) << 4;       // SWK
            *(u32x2*)&sm[OKK + o2] = (u32x2){pk0, pk1};
        }
    }
    __syncthreads();   // B4

    {
        const int mt = wv;
        short8 par = *(const short8*)&sm[OPR + (mt * 16 + (lane & 15)) * 64 + (lane >> 4) * 16];
        short8 pai = *(const short8*)&sm[OPI + (mt * 16 + (lane & 15)) * 64 + (lane >> 4) * 16];
        float w32r[4], w32i[4];
        #pragma unroll
        for (int rg = 0; rg < 4; ++rg) {
            int n = mt * 16 + (lane >> 4) * 4 + rg;
            float2 ww = *(const float2*)&sm[OW32 + n * 8];
            w32r[rg] = ww.x;
            w32i[rg] = ww.y;
        }
        f32x4 cr = (f32x4){0.f, 0.f, 0.f, 0.f};
        f32x4 ci_ = (f32x4){0.f, 0.f, 0.f, 0.f};
        const int colb = (lane & 15) >> 3;
        const int colr = lane & 7;
        #pragma unroll
        for (int g2 = 0; g2 < 8; ++g2) {
            int o = colb * 4096 + colr * 512 + g2 * 64 + (lane >> 4) * 16;
            o ^= ((o >> 9) & 7) << 4;         // SWK
            short8 kf = *(const short8*)&sm[OKK + o];
            f32x4 sre = __builtin_amdgcn_mfma_f32_16x16x32_bf16(par, kf, (f32x4){0.f,0.f,0.f,0.f}, 0, 0, 0);
            f32x4 sim = __builtin_amdgcn_mfma_f32_16x16x32_bf16(pai, kf, (f32x4){0.f,0.f,0.f,0.f}, 0, 0, 0);
            #pragma unroll
            for (int rg = 0; rg < 4; ++rg) {
                float wr = w32r[rg], wi = w32i[rg];
                float ncr = fmaf(cr[rg], wr, fmaf(-ci_[rg], wi, sre[rg]));
                float nci = fmaf(cr[rg], wi, fmaf(ci_[rg], wr, sim[rg]));
                cr[rg] = ncr;
                ci_[rg] = nci;
            }
        }
        __syncthreads();   // B5
        #pragma unroll
        for (int rg = 0; rg < 4; ++rg) {
            int n = mt * 16 + (lane >> 4) * 4 + rg;
            int c = lane & 15;
            ((float*)&sm[OKK])[n * 17 + c] = cr[rg];
            ((float*)&sm[OKK])[1088 + n * 17 + c] = ci_[rg];
        }
    }
    __syncthreads();   // B6

    if (t < 128) {
        const int n = t & 63, bl = t >> 6;
        const int b = bg * 2 + bl;
        float Are, Aim, lre, lim;
        get_disc(log_dt, log_A_real, A_imag, h, n, Are, Aim, lre, lim);
        float er = expf(lre), sn, cs;
        sincosf(lim, &sn, &cs);
        float wr = er * cs, wi = er * sn;
        float2 w32v = *(const float2*)&sm[OW32 + n * 8];
        float ar = w32v.x, ai = w32v.y;
        #pragma unroll
        for (int s = 0; s < 3; ++s) {
            float nr = ar * ar - ai * ai;
            ai = 2.f * ar * ai;
            ar = nr;
        }
        float den = Are * Are + Aim * Aim;
        float wm1r = wr - 1.f, wm1i = wi;
        float tr_ = (wm1r * Are + wm1i * Aim) / den;
        float ti_ = (wm1i * Are - wm1r * Aim) / den;
        float br = B_re[h * 64 + n], bi = B_im[h * 64 + n];
        float dBr = br * tr_ - bi * ti_;
        float dBi = br * ti_ + bi * tr_;
        const float* cre = (const float*)&sm[OKK] + n * 17 + bl * 8;
        const float* cim = (const float*)&sm[OKK] + 1088 + n * 17 + bl * 8;
        float sr = 0.f, si_ = 0.f;
        #pragma unroll
        for (int r = 0; r < 8; ++r) {
            float nsr = fmaf(ar, sr, fmaf(-ai, si_, cre[r]));
            float nsi = fmaf(ar, si_, fmaf(ai, sr, cim[r]));
            sr = nsr; si_ = nsi;
            out[(((size_t)b * NREC + r) * DM + h) * 64 + n] = dBr * sr - dBi * si_;
        }
    }
}

extern "C" void kernel_launch(void* const* d_in, const int* in_sizes, int n_in,
                              void* d_out, int out_size, void* d_ws, size_t ws_size,
                              hipStream_t stream)
{
    const float* u       = (const float*)d_in[0];
    const float* W       = (const float*)d_in[1];
    const float* bias    = (const float*)d_in[2];
    const float* shift_B = (const float*)d_in[3];
    const float* shift_C = (const float*)d_in[4];
    const float* ssm_k_D = (const float*)d_in[5];
    const float* log_dt  = (const float*)d_in[6];
    const float* log_Ar  = (const float*)d_in[7];
    const float* A_imag  = (const float*)d_in[8];
    const float* B_re    = (const float*)d_in[9];
    const float* B_im    = (const float*)d_in[10];
    float* out = (float*)d_out;

    unsigned short* klin = (unsigned short*)d_ws;   // 32 MB

    gemm_fused<<<dim3(256), 512, 0, stream>>>(W, u, bias, klin);

    expand<<<dim3(DM, 4), 256, 0, stream>>>(klin, shift_B, shift_C, ssm_k_D, log_dt,
                                            log_Ar, A_imag, B_re, B_im, out);
}